// Round 1
// baseline (542.068 us; speedup 1.0000x reference)
//
#include <hip/hip_runtime.h>

#define D_DIM 2048
#define K_DIM 64
#define T_DIM 2048
#define BT_DIM 16384   // B*T = 8*2048

// ---------------------------------------------------------------------------
// Kernel A: p[d,k] = softmax over k of w[d,:]. One wave per d row (lane = k).
// ---------------------------------------------------------------------------
__global__ __launch_bounds__(256) void softmax_k(const float* __restrict__ w,
                                                 float* __restrict__ p) {
    const int lane = threadIdx.x & 63;
    const int d = blockIdx.x * 4 + (threadIdx.x >> 6);
    float v = w[d * K_DIM + lane];
    float m = v;
#pragma unroll
    for (int off = 32; off > 0; off >>= 1) m = fmaxf(m, __shfl_xor(m, off, 64));
    float e = expf(v - m);
    float s = e;
#pragma unroll
    for (int off = 32; off > 0; off >>= 1) s += __shfl_xor(s, off, 64);
    p[d * K_DIM + lane] = e / s;
}

// ---------------------------------------------------------------------------
// Kernel B: per-column min/max of w, then nT[k,d] = (w[d,k]-mn)/(mx-mn).
// One block per k column.
// ---------------------------------------------------------------------------
__global__ __launch_bounds__(256) void norm_k(const float* __restrict__ w,
                                              float* __restrict__ nT) {
    const int k = blockIdx.x;
    const int lane = threadIdx.x & 63;
    const int wave = threadIdx.x >> 6;
    float mn = 1e30f, mx = -1e30f;
    for (int d = threadIdx.x; d < D_DIM; d += 256) {
        float v = w[d * K_DIM + k];
        mn = fminf(mn, v);
        mx = fmaxf(mx, v);
    }
#pragma unroll
    for (int off = 32; off > 0; off >>= 1) {
        mn = fminf(mn, __shfl_xor(mn, off, 64));
        mx = fmaxf(mx, __shfl_xor(mx, off, 64));
    }
    __shared__ float red[8];
    if (lane == 0) { red[wave] = mn; red[4 + wave] = mx; }
    __syncthreads();
    mn = fminf(fminf(red[0], red[1]), fminf(red[2], red[3]));
    mx = fmaxf(fmaxf(red[4], red[5]), fmaxf(red[6], red[7]));
    const float inv = 1.0f / (mx - mn);
    for (int d = threadIdx.x; d < D_DIM; d += 256) {
        nT[k * D_DIM + d] = (w[d * K_DIM + k] - mn) * inv;
    }
}

// ---------------------------------------------------------------------------
// Kernel C1: scores = X @ P (fp32 VALU), reduce to per-row (argmax, sign).
// One wave handles 16 consecutive rows with lane = k. stats[r] = ind | neg<<8.
// ---------------------------------------------------------------------------
__global__ __launch_bounds__(256) void gemm_stats_k(const float* __restrict__ x,
                                                    const float* __restrict__ p,
                                                    int* __restrict__ stats) {
    const int lane = threadIdx.x & 63;
    const int wave = threadIdx.x >> 6;
    const int r0 = (blockIdx.x * 4 + wave) * 16;
    float acc[16];
#pragma unroll
    for (int r = 0; r < 16; ++r) acc[r] = 0.0f;
    const float* xrow = x + (size_t)r0 * D_DIM;
    for (int d4 = 0; d4 < D_DIM; d4 += 4) {
        const float pv0 = p[(d4 + 0) * K_DIM + lane];
        const float pv1 = p[(d4 + 1) * K_DIM + lane];
        const float pv2 = p[(d4 + 2) * K_DIM + lane];
        const float pv3 = p[(d4 + 3) * K_DIM + lane];
#pragma unroll
        for (int r = 0; r < 16; ++r) {
            const float4 xv = *(const float4*)(xrow + (size_t)r * D_DIM + d4);
            float a = acc[r];
            a = fmaf(xv.x, pv0, a);
            a = fmaf(xv.y, pv1, a);
            a = fmaf(xv.z, pv2, a);
            a = fmaf(xv.w, pv3, a);
            acc[r] = a;
        }
    }
    // per-row 64-lane argmax (first index wins on ties, matching np.argmax)
#pragma unroll
    for (int r = 0; r < 16; ++r) {
        float v = acc[r];
        int idx = lane;
#pragma unroll
        for (int off = 32; off > 0; off >>= 1) {
            const float ov = __shfl_xor(v, off, 64);
            const int oi = __shfl_xor(idx, off, 64);
            if (ov > v || (ov == v && oi < idx)) { v = ov; idx = oi; }
        }
        if (lane == 0) stats[r0 + r] = idx | ((v < 0.0f) ? (1 << 8) : 0);
    }
}

// ---------------------------------------------------------------------------
// Kernel C2: out[r,d] = x[r,d] * (1 + W), W from stats[r-1]; rows t==0: W=0.
// One block per row, float4 vectorized.
// ---------------------------------------------------------------------------
__global__ __launch_bounds__(256) void output_k(const float* __restrict__ x,
                                                const float* __restrict__ nT,
                                                const int* __restrict__ stats,
                                                float* __restrict__ out) {
    const int row = blockIdx.x;
    const int t = row & (T_DIM - 1);
    const float4* x4 = (const float4*)(x + (size_t)row * D_DIM);
    float4* o4 = (float4*)(out + (size_t)row * D_DIM);
    if (t == 0) {
#pragma unroll
        for (int it = 0; it < 2; ++it) {
            const int i = threadIdx.x + it * 256;
            o4[i] = x4[i];
        }
        return;
    }
    const int s = stats[row - 1];
    const int ind = s & 0xff;
    const bool neg = (s >> 8) & 1;
    const float4* n4 = (const float4*)(nT + (size_t)ind * D_DIM);
#pragma unroll
    for (int it = 0; it < 2; ++it) {
        const int i = threadIdx.x + it * 256;
        const float4 xv = x4[i];
        const float4 nv = n4[i];
        float4 r;
        const float w0 = neg ? 1.0f - nv.x : nv.x;
        const float w1 = neg ? 1.0f - nv.y : nv.y;
        const float w2 = neg ? 1.0f - nv.z : nv.z;
        const float w3 = neg ? 1.0f - nv.w : nv.w;
        r.x = fmaf(xv.x, w0, xv.x);
        r.y = fmaf(xv.y, w1, xv.y);
        r.z = fmaf(xv.z, w2, xv.z);
        r.w = fmaf(xv.w, w3, xv.w);
        o4[i] = r;
    }
}

extern "C" void kernel_launch(void* const* d_in, const int* in_sizes, int n_in,
                              void* d_out, int out_size, void* d_ws, size_t ws_size,
                              hipStream_t stream) {
    const float* x = (const float*)d_in[0];   // [B,T,D] fp32
    const float* w = (const float*)d_in[1];   // [D,K] fp32
    float* out = (float*)d_out;

    float* p  = (float*)d_ws;                 // [D,K]  512 KB
    float* nT = p + D_DIM * K_DIM;            // [K,D]  512 KB
    int* stats = (int*)(nT + (size_t)K_DIM * D_DIM);  // [B*T] 64 KB

    softmax_k<<<D_DIM / 4, 256, 0, stream>>>(w, p);
    norm_k<<<K_DIM, 256, 0, stream>>>(w, nT);
    gemm_stats_k<<<BT_DIM / 64, 256, 0, stream>>>(x, p, stats);
    output_k<<<BT_DIM, 256, 0, stream>>>(x, nT, stats, out);
}